// Round 4
// baseline (495.915 us; speedup 1.0000x reference)
//
#include <hip/hip_runtime.h>

#define N_NODES 50000
#define N_EDGES 600000
#define HID 128

typedef __attribute__((ext_vector_type(8))) short bf16x8;
typedef __attribute__((ext_vector_type(8))) unsigned short u16x8;
typedef __attribute__((ext_vector_type(4))) float f32x4;

__device__ __forceinline__ float bf2f(unsigned short u) {
    return __uint_as_float(((unsigned int)u) << 16);
}
__device__ __forceinline__ unsigned short f2bf(float f) {
    unsigned int u = __float_as_uint(f);
    u = (u + 0x7FFFu + ((u >> 16) & 1u)) >> 16;   // RNE
    return (unsigned short)u;
}

// custom fp8: sign | 7-bit affine-log code (3-bit mantissa, exponents 2^-7..2^8)
// decode(v) bits = sign<<31 | (v + 0x3C0) << 20 ; v==0 -> 0.0
__device__ __forceinline__ unsigned fp8enc(float f) {
    unsigned u = __float_as_uint(f);
    unsigned s = (u >> 24) & 0x80u;
    unsigned m = u & 0x7fffffffu;
    unsigned r = m + 0x7FFFFu + ((m >> 20) & 1u);  // RNE at bit 20
    int v = (int)(r >> 20) - 0x3C0;
    v = v < 0 ? 0 : (v > 127 ? 127 : v);
    return s | (unsigned)v;
}
__device__ __forceinline__ float fp8dec(unsigned b) {
    unsigned v = b & 0x7fu;
    unsigned u = ((b & 0x80u) << 24) | ((v + 0x3C0u) << 20);
    return v ? __uint_as_float(u) : 0.0f;
}

// ---------------- preprocessing ----------------

// degcnt[i]: bits[43:63] = edge count, bits[0:42] = Q32.32 sum of attr (+1.0 self loop)
__global__ __launch_bounds__(256) void init_k(unsigned long long* degcnt, float* cs, int n) {
    int i = blockIdx.x * 256 + threadIdx.x;
    if (i < n) degcnt[i] = 1ull << 32;          // self-loop weight 1.0, count 0
    if (i < HID) cs[i] = 0.0f;
}

__global__ __launch_bounds__(256) void edge_deg_k(const int* __restrict__ edges,
                                                  const float* __restrict__ attr,
                                                  unsigned long long* degcnt,
                                                  int* __restrict__ rank) {
    int e = blockIdx.x * 256 + threadIdx.x;
    if (e < N_EDGES) {
        int c = edges[N_EDGES + e];             // target
        unsigned long long enc = (1ull << 43) +
            (unsigned long long)llrintf(attr[e] * 4294967296.0f);
        unsigned long long old = atomicAdd(&degcnt[c], enc);
        rank[e] = (int)(old >> 43);             // this edge's slot within its target
    }
}

// scan pass 1, fused with degcnt decode (cnt extract + dinv)
__global__ __launch_bounds__(256) void scan1_k(const unsigned long long* __restrict__ degcnt,
                                               int* offs, int* bsum, float* dinv, int n) {
    __shared__ int s[256];
    int tid = threadIdx.x;
    int i = blockIdx.x * 256 + tid;
    int v = 0;
    if (i < n) {
        unsigned long long dc = degcnt[i];
        v = (int)(dc >> 43);
        float deg = (float)(dc & ((1ull << 43) - 1)) * (1.0f / 4294967296.0f);
        dinv[i] = rsqrtf(deg);
    }
    s[tid] = v; __syncthreads();
    for (int d = 1; d < 256; d <<= 1) {
        int t = (tid >= d) ? s[tid - d] : 0;
        __syncthreads();
        s[tid] += t;
        __syncthreads();
    }
    if (i < n) offs[i] = s[tid] - v;
    if (tid == 255) bsum[blockIdx.x] = s[255];
}

__global__ __launch_bounds__(256) void scan2_k(int* bsum, int nb) {
    __shared__ int s[256];
    int t = threadIdx.x;
    int v = (t < nb) ? bsum[t] : 0;
    s[t] = v; __syncthreads();
    for (int d = 1; d < 256; d <<= 1) {
        int u = (t >= d) ? s[t - d] : 0;
        __syncthreads();
        s[t] += u;
        __syncthreads();
    }
    if (t < nb) bsum[t] = s[t] - v;
}

__global__ __launch_bounds__(256) void scan3_k(int* offs, const int* __restrict__ bsum, int n) {
    int i = blockIdx.x * 256 + threadIdx.x;
    if (i < n) offs[i] += bsum[blockIdx.x];
}

// no atomics: slot = offs[target] + rank[e]
__global__ __launch_bounds__(256) void fill_k(const int* __restrict__ edges,
                                              const float* __restrict__ attr,
                                              const float* __restrict__ dinv,
                                              const int* __restrict__ offs,
                                              const int* __restrict__ rank,
                                              int2* __restrict__ epk) {
    int e = blockIdx.x * 256 + threadIdx.x;
    if (e < N_EDGES) {
        int r = edges[e];                    // source
        int c = edges[N_EDGES + e];          // target
        float w = dinv[r] * attr[e] * dinv[c];
        epk[offs[c] + rank[e]] = make_int2(r, __float_as_int(w));
    }
}

// W^T bf16 hi/lo split for 5 layers: Wt[l][n][k] = W_l[k][n]
__global__ __launch_bounds__(256) void prep_w_k(const float* __restrict__ W1,
                                                const float* __restrict__ Ws,
                                                unsigned short* __restrict__ Wt_hi,
                                                unsigned short* __restrict__ Wt_lo) {
    int i = blockIdx.x * 256 + threadIdx.x;
    if (i >= 5 * 16384) return;
    int l = i >> 14;
    int r = i & 16383;
    int n = r >> 7;
    int k = r & 127;
    const float* src = (l == 0) ? W1 : (Ws + (size_t)(l - 1) * 16384);
    float w = src[k * 128 + n];
    unsigned short hi = f2bf(w);
    unsigned short lo = f2bf(w - bf2f(hi));
    Wt_hi[i] = hi;
    Wt_lo[i] = lo;
}

// fp32 -> bf16 bulk convert (4 elems/thread)
__global__ __launch_bounds__(256) void cvt_bf_k(const float* __restrict__ x,
                                                unsigned short* __restrict__ y, int n4) {
    int i = blockIdx.x * 256 + threadIdx.x;
    if (i < n4) {
        float4 v = ((const float4*)x)[i];
        ushort4 o;
        o.x = f2bf(v.x); o.y = f2bf(v.y); o.z = f2bf(v.z); o.w = f2bf(v.w);
        ((ushort4*)y)[i] = o;
    }
}

// ---------------- MFMA GEMM: H[n x 128] = A[n x 128] @ (W_hi + W_lo), fp8 out ----------------

__global__ __launch_bounds__(256) void mfma_gemm_k(const unsigned short* __restrict__ A,
                                                   const unsigned short* __restrict__ Bh,
                                                   const unsigned short* __restrict__ Bl,
                                                   unsigned char* __restrict__ H, int nrows) {
    int wid  = threadIdx.x >> 6;
    int lane = threadIdx.x & 63;
    int row0 = blockIdx.x * 64 + wid * 16;
    int rl = lane & 15;          // A row within tile / B col
    int kg = lane >> 4;          // k-group (8 elems each)

    int row = row0 + rl;
    int ar  = row < nrows ? row : nrows - 1;

    bf16x8 af[4];
    #pragma unroll
    for (int kt = 0; kt < 4; ++kt)
        af[kt] = *(const bf16x8*)(A + (size_t)ar * HID + kt * 32 + kg * 8);

    f32x4 acc[8];
    #pragma unroll
    for (int nt = 0; nt < 8; ++nt) acc[nt] = (f32x4){0.f, 0.f, 0.f, 0.f};

    #pragma unroll
    for (int nt = 0; nt < 8; ++nt) {
        #pragma unroll
        for (int kt = 0; kt < 4; ++kt) {
            size_t boff = (size_t)(nt * 16 + rl) * HID + kt * 32 + kg * 8;
            bf16x8 bh = *(const bf16x8*)(Bh + boff);
            acc[nt] = __builtin_amdgcn_mfma_f32_16x16x32_bf16(af[kt], bh, acc[nt], 0, 0, 0);
            bf16x8 bl = *(const bf16x8*)(Bl + boff);
            acc[nt] = __builtin_amdgcn_mfma_f32_16x16x32_bf16(af[kt], bl, acc[nt], 0, 0, 0);
        }
    }

    // D: col = lane&15, row = (lane>>4)*4 + reg
    #pragma unroll
    for (int nt = 0; nt < 8; ++nt) {
        #pragma unroll
        for (int r = 0; r < 4; ++r) {
            int orow = row0 + kg * 4 + r;
            if (orow < nrows)
                H[(size_t)orow * HID + nt * 16 + rl] = (unsigned char)fp8enc(acc[nt][r]);
        }
    }
}

// ---------------- aggregation: one wave per node, 4 edges/iter, fp8 gather ----------------

__global__ __launch_bounds__(256) void aggregate_k(const unsigned char* __restrict__ h,
                                                   const int* __restrict__ offs,
                                                   const int2* __restrict__ epk,
                                                   const float* __restrict__ dinv,
                                                   const float* __restrict__ bias,
                                                   const unsigned short* __restrict__ xprev,
                                                   unsigned short* __restrict__ xout, int n) {
    int w = (blockIdx.x * 256 + threadIdx.x) >> 6;
    if (w >= n) return;
    int lane = threadIdx.x & 63;
    int g  = lane >> 4;                      // edge group 0..3
    int ci = (lane & 15) * 8;                // 8 columns per lane (8 bytes fp8)

    float a[8];
    #pragma unroll
    for (int j = 0; j < 8; ++j) a[j] = 0.f;

    int e0 = offs[w];
    int e1 = (w + 1 < n) ? offs[w + 1] : N_EDGES;

    for (int e = e0 + g; e < e1; e += 4) {
        int2 pk = epk[e];
        float wt = __int_as_float(pk.y);
        uint2 q = *(const uint2*)(h + (size_t)pk.x * HID + ci);
        #pragma unroll
        for (int j = 0; j < 4; ++j) {
            a[j]     = fmaf(fp8dec((q.x >> (8 * j)) & 0xffu), wt, a[j]);
            a[j + 4] = fmaf(fp8dec((q.y >> (8 * j)) & 0xffu), wt, a[j + 4]);
        }
    }

    #pragma unroll
    for (int j = 0; j < 8; ++j) a[j] += __shfl_xor(a[j], 16);
    #pragma unroll
    for (int j = 0; j < 8; ++j) a[j] += __shfl_xor(a[j], 32);

    if (g == 0) {
        float di = dinv[w];
        float d2 = di * di;
        uint2 qw = *(const uint2*)(h + (size_t)w * HID + ci);
        #pragma unroll
        for (int j = 0; j < 4; ++j) {
            a[j]     = fmaf(fp8dec((qw.x >> (8 * j)) & 0xffu), d2, a[j]);
            a[j + 4] = fmaf(fp8dec((qw.y >> (8 * j)) & 0xffu), d2, a[j + 4]);
        }
        float4 b0 = *(const float4*)(bias + ci);
        float4 b1 = *(const float4*)(bias + ci + 4);
        a[0] += b0.x; a[1] += b0.y; a[2] += b0.z; a[3] += b0.w;
        a[4] += b1.x; a[5] += b1.y; a[6] += b1.z; a[7] += b1.w;
        if (xprev) {
            u16x8 xp = *(const u16x8*)(xprev + (size_t)w * HID + ci);
            #pragma unroll
            for (int j = 0; j < 8; ++j) a[j] += bf2f(xp[j]);
        }
        u16x8 o;
        #pragma unroll
        for (int j = 0; j < 8; ++j) o[j] = f2bf(fmaxf(a[j], 0.f));
        *(u16x8*)(xout + (size_t)w * HID + ci) = o;
    }
}

// ---------------- final head ----------------

__global__ __launch_bounds__(128) void colsum_k(const unsigned short* __restrict__ x, float* cs, int n) {
    int col = threadIdx.x;  // 128 threads
    float acc = 0.f;
    for (int r = blockIdx.x; r < n; r += gridDim.x)
        acc += bf2f(x[(size_t)r * HID + col]);
    atomicAdd(&cs[col], acc);
}

__global__ __launch_bounds__(128) void final_k(const float* __restrict__ cs,
                                               const float* __restrict__ Wfc,
                                               const float* __restrict__ bfc,
                                               float* __restrict__ out) {
    __shared__ float s0[128], s1[128];
    int k = threadIdx.x;
    float c = cs[k];
    s0[k] = c * Wfc[k * 2 + 0];
    s1[k] = c * Wfc[k * 2 + 1];
    __syncthreads();
    for (int d = 64; d > 0; d >>= 1) {
        if (k < d) { s0[k] += s0[k + d]; s1[k] += s1[k + d]; }
        __syncthreads();
    }
    if (k == 0) {
        out[0] = s0[0] / (float)N_NODES + bfc[0];
        out[1] = s1[0] / (float)N_NODES + bfc[1];
    }
}

// ---------------- host ----------------

extern "C" void kernel_launch(void* const* d_in, const int* in_sizes, int n_in,
                              void* d_out, int out_size, void* d_ws, size_t ws_size,
                              hipStream_t stream) {
    const float* node  = (const float*)d_in[0];
    const int*   edges = (const int*)d_in[1];     // [2, E] int32
    const float* attr  = (const float*)d_in[2];
    const float* W1    = (const float*)d_in[3];
    const float* b1    = (const float*)d_in[4];
    const float* Ws    = (const float*)d_in[5];   // [4,128,128]
    const float* bs    = (const float*)d_in[6];   // [4,128]
    const float* Wfc   = (const float*)d_in[7];   // [128,2]
    const float* bfc   = (const float*)d_in[8];
    float* out = (float*)d_out;

    char* ws = (char*)d_ws;
    const size_t BN = (size_t)N_NODES * HID * 2;  // 12.8 MB bf16 plane
    unsigned char*  h8     = (unsigned char*)(ws);                 // 6.4 MB fp8
    unsigned short* xa_bf  = (unsigned short*)(ws + BN);
    unsigned short* xb_bf  = (unsigned short*)(ws + 2 * BN);
    unsigned short* nd_bf  = (unsigned short*)(ws + 3 * BN);
    char* p = ws + 4 * BN;
    unsigned long long* degcnt = (unsigned long long*)p; p += (size_t)N_NODES * 8;
    float* dinv  = (float*)p;            p += N_NODES * 4;
    int*   offs  = (int*)p;              p += N_NODES * 4;
    int*   rank  = (int*)p;              p += (size_t)N_EDGES * 4;
    int*   bsum  = (int*)p;              p += 1024;
    int2*  epk   = (int2*)p;             p += (size_t)N_EDGES * 8;
    float* cs    = (float*)p;            p += 512;
    unsigned short* wt_hi = (unsigned short*)p;  p += 5 * 16384 * 2;
    unsigned short* wt_lo = (unsigned short*)p;  p += 5 * 16384 * 2;

    const int NB_N = (N_NODES + 255) / 256;   // 196
    const int NB_E = (N_EDGES + 255) / 256;   // 2344

    hipLaunchKernelGGL(init_k,    dim3(NB_N), dim3(256), 0, stream, degcnt, cs, N_NODES);
    hipLaunchKernelGGL(edge_deg_k,dim3(NB_E), dim3(256), 0, stream, edges, attr, degcnt, rank);
    hipLaunchKernelGGL(scan1_k,   dim3(NB_N), dim3(256), 0, stream, degcnt, offs, bsum, dinv, N_NODES);
    hipLaunchKernelGGL(scan2_k,   dim3(1),    dim3(256), 0, stream, bsum, NB_N);
    hipLaunchKernelGGL(scan3_k,   dim3(NB_N), dim3(256), 0, stream, offs, bsum, N_NODES);
    hipLaunchKernelGGL(fill_k,    dim3(NB_E), dim3(256), 0, stream, edges, attr, dinv, offs, rank, epk);
    hipLaunchKernelGGL(prep_w_k,  dim3(320),  dim3(256), 0, stream, W1, Ws, wt_hi, wt_lo);
    hipLaunchKernelGGL(cvt_bf_k,  dim3(6250), dim3(256), 0, stream, node, nd_bf, N_NODES * HID / 4);

    const int GB = (N_NODES + 63) / 64;       // 782
    const int AB = (N_NODES * 64) / 256;      // 12500

    // layer 1
    hipLaunchKernelGGL(mfma_gemm_k, dim3(GB), dim3(256), 0, stream, nd_bf, wt_hi, wt_lo, h8, N_NODES);
    hipLaunchKernelGGL(aggregate_k, dim3(AB), dim3(256), 0, stream, h8, offs, epk, dinv,
                       b1, (const unsigned short*)nullptr, xa_bf, N_NODES);

    // 4 residual steps
    unsigned short* xc = xa_bf;
    unsigned short* xn = xb_bf;
    for (int i = 0; i < 4; ++i) {
        hipLaunchKernelGGL(mfma_gemm_k, dim3(GB), dim3(256), 0, stream,
                           xc, wt_hi + (size_t)(i + 1) * 16384, wt_lo + (size_t)(i + 1) * 16384,
                           h8, N_NODES);
        hipLaunchKernelGGL(aggregate_k, dim3(AB), dim3(256), 0, stream, h8, offs, epk, dinv,
                           bs + (size_t)i * HID, xc, xn, N_NODES);
        unsigned short* t = xc; xc = xn; xn = t;
    }

    hipLaunchKernelGGL(colsum_k, dim3(512), dim3(128), 0, stream, xc, cs, N_NODES);
    hipLaunchKernelGGL(final_k,  dim3(1),   dim3(128), 0, stream, cs, Wfc, bfc, out);
}

// Round 5
// 440.032 us; speedup vs baseline: 1.1270x; 1.1270x over previous
//
#include <hip/hip_runtime.h>

#define N_NODES 50000
#define N_EDGES 600000
#define HID 128

typedef __attribute__((ext_vector_type(8))) short bf16x8;
typedef __attribute__((ext_vector_type(8))) unsigned short u16x8;
typedef __attribute__((ext_vector_type(4))) float f32x4;
typedef __attribute__((ext_vector_type(2))) float f32x2;

__device__ __forceinline__ float bf2f(unsigned short u) {
    return __uint_as_float(((unsigned int)u) << 16);
}
__device__ __forceinline__ unsigned short f2bf(float f) {
    unsigned int u = __float_as_uint(f);
    u = (u + 0x7FFFu + ((u >> 16) & 1u)) >> 16;   // RNE
    return (unsigned short)u;
}

// hardware OCP e4m3 fp8 encode (single value -> byte)
__device__ __forceinline__ unsigned char fp8enc_hw(float f) {
    return (unsigned char)(__builtin_amdgcn_cvt_pk_fp8_f32(f, f, 0, false) & 0xff);
}

// ---------------- preprocessing ----------------

// degcnt[i]: bits[43:63] = edge count, bits[0:42] = Q32.32 sum of attr (+1.0 self loop)
__global__ __launch_bounds__(256) void init_k(unsigned long long* degcnt, float* cs, int n) {
    int i = blockIdx.x * 256 + threadIdx.x;
    if (i < n) degcnt[i] = 1ull << 32;          // self-loop weight 1.0, count 0
    if (i < HID) cs[i] = 0.0f;
}

__global__ __launch_bounds__(256) void edge_deg_k(const int* __restrict__ edges,
                                                  const float* __restrict__ attr,
                                                  unsigned long long* degcnt,
                                                  int* __restrict__ rank) {
    int e = blockIdx.x * 256 + threadIdx.x;
    if (e < N_EDGES) {
        int c = edges[N_EDGES + e];             // target
        unsigned long long enc = (1ull << 43) +
            (unsigned long long)llrintf(attr[e] * 4294967296.0f);
        unsigned long long old = atomicAdd(&degcnt[c], enc);
        rank[e] = (int)(old >> 43);             // this edge's slot within its target
    }
}

// scan pass 1, fused with degcnt decode (cnt extract + dinv)
__global__ __launch_bounds__(256) void scan1_k(const unsigned long long* __restrict__ degcnt,
                                               int* offs, int* bsum, float* dinv, int n) {
    __shared__ int s[256];
    int tid = threadIdx.x;
    int i = blockIdx.x * 256 + tid;
    int v = 0;
    if (i < n) {
        unsigned long long dc = degcnt[i];
        v = (int)(dc >> 43);
        float deg = (float)(dc & ((1ull << 43) - 1)) * (1.0f / 4294967296.0f);
        dinv[i] = rsqrtf(deg);
    }
    s[tid] = v; __syncthreads();
    for (int d = 1; d < 256; d <<= 1) {
        int t = (tid >= d) ? s[tid - d] : 0;
        __syncthreads();
        s[tid] += t;
        __syncthreads();
    }
    if (i < n) offs[i] = s[tid] - v;
    if (tid == 255) bsum[blockIdx.x] = s[255];
}

__global__ __launch_bounds__(256) void scan2_k(int* bsum, int nb) {
    __shared__ int s[256];
    int t = threadIdx.x;
    int v = (t < nb) ? bsum[t] : 0;
    s[t] = v; __syncthreads();
    for (int d = 1; d < 256; d <<= 1) {
        int u = (t >= d) ? s[t - d] : 0;
        __syncthreads();
        s[t] += u;
        __syncthreads();
    }
    if (t < nb) bsum[t] = s[t] - v;
}

__global__ __launch_bounds__(256) void scan3_k(int* offs, const int* __restrict__ bsum, int n) {
    int i = blockIdx.x * 256 + threadIdx.x;
    if (i < n) offs[i] += bsum[blockIdx.x];
}

// no atomics: slot = offs[target] + rank[e]
__global__ __launch_bounds__(256) void fill_k(const int* __restrict__ edges,
                                              const float* __restrict__ attr,
                                              const float* __restrict__ dinv,
                                              const int* __restrict__ offs,
                                              const int* __restrict__ rank,
                                              int2* __restrict__ epk) {
    int e = blockIdx.x * 256 + threadIdx.x;
    if (e < N_EDGES) {
        int r = edges[e];                    // source
        int c = edges[N_EDGES + e];          // target
        float w = dinv[r] * attr[e] * dinv[c];
        epk[offs[c] + rank[e]] = make_int2(r, __float_as_int(w));
    }
}

// W^T bf16 hi/lo split for 5 layers: Wt[l][n][k] = W_l[k][n]
__global__ __launch_bounds__(256) void prep_w_k(const float* __restrict__ W1,
                                                const float* __restrict__ Ws,
                                                unsigned short* __restrict__ Wt_hi,
                                                unsigned short* __restrict__ Wt_lo) {
    int i = blockIdx.x * 256 + threadIdx.x;
    if (i >= 5 * 16384) return;
    int l = i >> 14;
    int r = i & 16383;
    int n = r >> 7;
    int k = r & 127;
    const float* src = (l == 0) ? W1 : (Ws + (size_t)(l - 1) * 16384);
    float w = src[k * 128 + n];
    unsigned short hi = f2bf(w);
    unsigned short lo = f2bf(w - bf2f(hi));
    Wt_hi[i] = hi;
    Wt_lo[i] = lo;
}

// fp32 -> bf16 bulk convert (4 elems/thread)
__global__ __launch_bounds__(256) void cvt_bf_k(const float* __restrict__ x,
                                                unsigned short* __restrict__ y, int n4) {
    int i = blockIdx.x * 256 + threadIdx.x;
    if (i < n4) {
        float4 v = ((const float4*)x)[i];
        ushort4 o;
        o.x = f2bf(v.x); o.y = f2bf(v.y); o.z = f2bf(v.z); o.w = f2bf(v.w);
        ((ushort4*)y)[i] = o;
    }
}

// ---------------- MFMA GEMM: H[n x 128] = A[n x 128] @ (W_hi + W_lo), fp8 out ----------------

__global__ __launch_bounds__(256) void mfma_gemm_k(const unsigned short* __restrict__ A,
                                                   const unsigned short* __restrict__ Bh,
                                                   const unsigned short* __restrict__ Bl,
                                                   unsigned char* __restrict__ H, int nrows) {
    int wid  = threadIdx.x >> 6;
    int lane = threadIdx.x & 63;
    int row0 = blockIdx.x * 64 + wid * 16;
    int rl = lane & 15;          // A row within tile / B col
    int kg = lane >> 4;          // k-group (8 elems each)

    int row = row0 + rl;
    int ar  = row < nrows ? row : nrows - 1;

    bf16x8 af[4];
    #pragma unroll
    for (int kt = 0; kt < 4; ++kt)
        af[kt] = *(const bf16x8*)(A + (size_t)ar * HID + kt * 32 + kg * 8);

    f32x4 acc[8];
    #pragma unroll
    for (int nt = 0; nt < 8; ++nt) acc[nt] = (f32x4){0.f, 0.f, 0.f, 0.f};

    #pragma unroll
    for (int nt = 0; nt < 8; ++nt) {
        #pragma unroll
        for (int kt = 0; kt < 4; ++kt) {
            size_t boff = (size_t)(nt * 16 + rl) * HID + kt * 32 + kg * 8;
            bf16x8 bh = *(const bf16x8*)(Bh + boff);
            acc[nt] = __builtin_amdgcn_mfma_f32_16x16x32_bf16(af[kt], bh, acc[nt], 0, 0, 0);
            bf16x8 bl = *(const bf16x8*)(Bl + boff);
            acc[nt] = __builtin_amdgcn_mfma_f32_16x16x32_bf16(af[kt], bl, acc[nt], 0, 0, 0);
        }
    }

    // D: col = lane&15, row = (lane>>4)*4 + reg
    #pragma unroll
    for (int nt = 0; nt < 8; ++nt) {
        #pragma unroll
        for (int r = 0; r < 4; ++r) {
            int orow = row0 + kg * 4 + r;
            if (orow < nrows)
                H[(size_t)orow * HID + nt * 16 + rl] = fp8enc_hw(acc[nt][r]);
        }
    }
}

// ---------------- aggregation: one wave per node, 4 edges/iter, fp8 gather + HW decode ----------------

__global__ __launch_bounds__(256) void aggregate_k(const unsigned char* __restrict__ h,
                                                   const int* __restrict__ offs,
                                                   const int2* __restrict__ epk,
                                                   const float* __restrict__ dinv,
                                                   const float* __restrict__ bias,
                                                   const unsigned short* __restrict__ xprev,
                                                   unsigned short* __restrict__ xout, int n) {
    int w = (blockIdx.x * 256 + threadIdx.x) >> 6;
    if (w >= n) return;
    int lane = threadIdx.x & 63;
    int g  = lane >> 4;                      // edge group 0..3
    int ci = (lane & 15) * 8;                // 8 columns per lane (8 bytes fp8)

    float a[8];
    #pragma unroll
    for (int j = 0; j < 8; ++j) a[j] = 0.f;

    int e0 = offs[w];
    int e1 = (w + 1 < n) ? offs[w + 1] : N_EDGES;

    for (int e = e0 + g; e < e1; e += 4) {
        int2 pk = epk[e];
        float wt = __int_as_float(pk.y);
        uint2 q = *(const uint2*)(h + (size_t)pk.x * HID + ci);
        f32x2 f01 = __builtin_amdgcn_cvt_pk_f32_fp8((int)q.x, false);
        f32x2 f23 = __builtin_amdgcn_cvt_pk_f32_fp8((int)q.x, true);
        f32x2 f45 = __builtin_amdgcn_cvt_pk_f32_fp8((int)q.y, false);
        f32x2 f67 = __builtin_amdgcn_cvt_pk_f32_fp8((int)q.y, true);
        a[0] = fmaf(f01.x, wt, a[0]); a[1] = fmaf(f01.y, wt, a[1]);
        a[2] = fmaf(f23.x, wt, a[2]); a[3] = fmaf(f23.y, wt, a[3]);
        a[4] = fmaf(f45.x, wt, a[4]); a[5] = fmaf(f45.y, wt, a[5]);
        a[6] = fmaf(f67.x, wt, a[6]); a[7] = fmaf(f67.y, wt, a[7]);
    }

    #pragma unroll
    for (int j = 0; j < 8; ++j) a[j] += __shfl_xor(a[j], 16);
    #pragma unroll
    for (int j = 0; j < 8; ++j) a[j] += __shfl_xor(a[j], 32);

    if (g == 0) {
        float di = dinv[w];
        float d2 = di * di;
        uint2 qw = *(const uint2*)(h + (size_t)w * HID + ci);
        f32x2 f01 = __builtin_amdgcn_cvt_pk_f32_fp8((int)qw.x, false);
        f32x2 f23 = __builtin_amdgcn_cvt_pk_f32_fp8((int)qw.x, true);
        f32x2 f45 = __builtin_amdgcn_cvt_pk_f32_fp8((int)qw.y, false);
        f32x2 f67 = __builtin_amdgcn_cvt_pk_f32_fp8((int)qw.y, true);
        a[0] = fmaf(f01.x, d2, a[0]); a[1] = fmaf(f01.y, d2, a[1]);
        a[2] = fmaf(f23.x, d2, a[2]); a[3] = fmaf(f23.y, d2, a[3]);
        a[4] = fmaf(f45.x, d2, a[4]); a[5] = fmaf(f45.y, d2, a[5]);
        a[6] = fmaf(f67.x, d2, a[6]); a[7] = fmaf(f67.y, d2, a[7]);
        float4 b0 = *(const float4*)(bias + ci);
        float4 b1 = *(const float4*)(bias + ci + 4);
        a[0] += b0.x; a[1] += b0.y; a[2] += b0.z; a[3] += b0.w;
        a[4] += b1.x; a[5] += b1.y; a[6] += b1.z; a[7] += b1.w;
        if (xprev) {
            u16x8 xp = *(const u16x8*)(xprev + (size_t)w * HID + ci);
            #pragma unroll
            for (int j = 0; j < 8; ++j) a[j] += bf2f(xp[j]);
        }
        u16x8 o;
        #pragma unroll
        for (int j = 0; j < 8; ++j) o[j] = f2bf(fmaxf(a[j], 0.f));
        *(u16x8*)(xout + (size_t)w * HID + ci) = o;
    }
}

// ---------------- final head ----------------

__global__ __launch_bounds__(128) void colsum_k(const unsigned short* __restrict__ x, float* cs, int n) {
    int col = threadIdx.x;  // 128 threads
    float acc = 0.f;
    for (int r = blockIdx.x; r < n; r += gridDim.x)
        acc += bf2f(x[(size_t)r * HID + col]);
    atomicAdd(&cs[col], acc);
}

__global__ __launch_bounds__(128) void final_k(const float* __restrict__ cs,
                                               const float* __restrict__ Wfc,
                                               const float* __restrict__ bfc,
                                               float* __restrict__ out) {
    __shared__ float s0[128], s1[128];
    int k = threadIdx.x;
    float c = cs[k];
    s0[k] = c * Wfc[k * 2 + 0];
    s1[k] = c * Wfc[k * 2 + 1];
    __syncthreads();
    for (int d = 64; d > 0; d >>= 1) {
        if (k < d) { s0[k] += s0[k + d]; s1[k] += s1[k + d]; }
        __syncthreads();
    }
    if (k == 0) {
        out[0] = s0[0] / (float)N_NODES + bfc[0];
        out[1] = s1[0] / (float)N_NODES + bfc[1];
    }
}

// ---------------- host ----------------

extern "C" void kernel_launch(void* const* d_in, const int* in_sizes, int n_in,
                              void* d_out, int out_size, void* d_ws, size_t ws_size,
                              hipStream_t stream) {
    const float* node  = (const float*)d_in[0];
    const int*   edges = (const int*)d_in[1];     // [2, E] int32
    const float* attr  = (const float*)d_in[2];
    const float* W1    = (const float*)d_in[3];
    const float* b1    = (const float*)d_in[4];
    const float* Ws    = (const float*)d_in[5];   // [4,128,128]
    const float* bs    = (const float*)d_in[6];   // [4,128]
    const float* Wfc   = (const float*)d_in[7];   // [128,2]
    const float* bfc   = (const float*)d_in[8];
    float* out = (float*)d_out;

    char* ws = (char*)d_ws;
    const size_t BN = (size_t)N_NODES * HID * 2;  // 12.8 MB bf16 plane
    unsigned char*  h8     = (unsigned char*)(ws);                 // 6.4 MB fp8
    unsigned short* xa_bf  = (unsigned short*)(ws + BN);
    unsigned short* xb_bf  = (unsigned short*)(ws + 2 * BN);
    unsigned short* nd_bf  = (unsigned short*)(ws + 3 * BN);
    char* p = ws + 4 * BN;
    unsigned long long* degcnt = (unsigned long long*)p; p += (size_t)N_NODES * 8;
    float* dinv  = (float*)p;            p += N_NODES * 4;
    int*   offs  = (int*)p;              p += N_NODES * 4;
    int*   rank  = (int*)p;              p += (size_t)N_EDGES * 4;
    int*   bsum  = (int*)p;              p += 1024;
    int2*  epk   = (int2*)p;             p += (size_t)N_EDGES * 8;
    float* cs    = (float*)p;            p += 512;
    unsigned short* wt_hi = (unsigned short*)p;  p += 5 * 16384 * 2;
    unsigned short* wt_lo = (unsigned short*)p;  p += 5 * 16384 * 2;

    const int NB_N = (N_NODES + 255) / 256;   // 196
    const int NB_E = (N_EDGES + 255) / 256;   // 2344

    hipLaunchKernelGGL(init_k,    dim3(NB_N), dim3(256), 0, stream, degcnt, cs, N_NODES);
    hipLaunchKernelGGL(edge_deg_k,dim3(NB_E), dim3(256), 0, stream, edges, attr, degcnt, rank);
    hipLaunchKernelGGL(scan1_k,   dim3(NB_N), dim3(256), 0, stream, degcnt, offs, bsum, dinv, N_NODES);
    hipLaunchKernelGGL(scan2_k,   dim3(1),    dim3(256), 0, stream, bsum, NB_N);
    hipLaunchKernelGGL(scan3_k,   dim3(NB_N), dim3(256), 0, stream, offs, bsum, N_NODES);
    hipLaunchKernelGGL(fill_k,    dim3(NB_E), dim3(256), 0, stream, edges, attr, dinv, offs, rank, epk);
    hipLaunchKernelGGL(prep_w_k,  dim3(320),  dim3(256), 0, stream, W1, Ws, wt_hi, wt_lo);
    hipLaunchKernelGGL(cvt_bf_k,  dim3(6250), dim3(256), 0, stream, node, nd_bf, N_NODES * HID / 4);

    const int GB = (N_NODES + 63) / 64;       // 782
    const int AB = (N_NODES * 64) / 256;      // 12500

    // layer 1
    hipLaunchKernelGGL(mfma_gemm_k, dim3(GB), dim3(256), 0, stream, nd_bf, wt_hi, wt_lo, h8, N_NODES);
    hipLaunchKernelGGL(aggregate_k, dim3(AB), dim3(256), 0, stream, h8, offs, epk, dinv,
                       b1, (const unsigned short*)nullptr, xa_bf, N_NODES);

    // 4 residual steps
    unsigned short* xc = xa_bf;
    unsigned short* xn = xb_bf;
    for (int i = 0; i < 4; ++i) {
        hipLaunchKernelGGL(mfma_gemm_k, dim3(GB), dim3(256), 0, stream,
                           xc, wt_hi + (size_t)(i + 1) * 16384, wt_lo + (size_t)(i + 1) * 16384,
                           h8, N_NODES);
        hipLaunchKernelGGL(aggregate_k, dim3(AB), dim3(256), 0, stream, h8, offs, epk, dinv,
                           bs + (size_t)i * HID, xc, xn, N_NODES);
        unsigned short* t = xc; xc = xn; xn = t;
    }

    hipLaunchKernelGGL(colsum_k, dim3(512), dim3(128), 0, stream, xc, cs, N_NODES);
    hipLaunchKernelGGL(final_k,  dim3(1),   dim3(128), 0, stream, cs, Wfc, bfc, out);
}